// Round 6
// baseline (232.085 us; speedup 1.0000x reference)
//
#include <hip/hip_runtime.h>
#include <stdint.h>

#define NB 256
#define NL 128
#define ND1 512
#define ND2 512
#define NE 64

#define BI 128              // i-tile width per block
#define BK 128              // k-tile depth (j-dim)
#define NKT (ND2 / BK)      // 4 k-tiles
#define LDSTB 136           // B LDS row stride (bf16 elems): 272 B rows, same bank phase as proven LDST=72 (+4 banks/row)

typedef float float4_t __attribute__((ext_vector_type(4)));
typedef __bf16 bf16x8_t __attribute__((ext_vector_type(8)));
typedef unsigned short ushort4_t __attribute__((ext_vector_type(4)));
typedef unsigned short ushort8_t __attribute__((ext_vector_type(8)));

// fp32 -> bf16 round-to-nearest-even
__device__ __forceinline__ unsigned short f2bf(float f) {
    unsigned int u = __float_as_uint(f);
    u += 0x7FFFu + ((u >> 16) & 1u);
    return (unsigned short)(u >> 16);
}

__device__ __forceinline__ ushort4_t cvt4(float4_t v) {
    ushort4_t u;
    u.x = f2bf(v.x); u.y = f2bf(v.y); u.z = f2bf(v.z); u.w = f2bf(v.w);
    return u;
}

// pack two float4 (8 contiguous k-elems) into one bf16x8 MFMA A-fragment
__device__ __forceinline__ bf16x8_t cvt8(float4_t a, float4_t b) {
    ushort8_t u;
    u[0] = f2bf(a.x); u[1] = f2bf(a.y); u[2] = f2bf(a.z); u[3] = f2bf(a.w);
    u[4] = f2bf(b.x); u[5] = f2bf(b.y); u[6] = f2bf(b.z); u[7] = f2bf(b.w);
    return __builtin_bit_cast(bf16x8_t, u);
}

// Pre-pass: zero output + counting-sort batches by expert id -> perm.
__global__ void pre_kernel(const int* __restrict__ pidx, int* __restrict__ perm,
                           float* __restrict__ out, int zero_n, int do_sort)
{
    const int g = blockIdx.x, t = threadIdx.x;
    const int idx = g * 256 + t;
    if (idx < zero_n) out[idx] = 0.f;
    if (do_sort && g == 0) {
        __shared__ int cnt[NE];
        __shared__ int base[NE];
        if (t < NE) cnt[t] = 0;
        __syncthreads();
        const int e = pidx[t];
        const int r = atomicAdd(&cnt[e], 1);
        __syncthreads();
        if (t == 0) {
            int s = 0;
            for (int i = 0; i < NE; ++i) { base[i] = s; s += cnt[i]; }
        }
        __syncthreads();
        perm[base[e] + r] = t;
    }
}

// Z = T2 (128 x 512) x W^T; out[b,l] = sum_i Z[l,i] * t1[b,l,i]
//
// BI=128, BK=128, 512 threads, grid 1024 = 2 blocks/CU x 2 rounds.
// 8 waves = 4(wv) x 2(ih). A-operand (t2) is NOT staged in LDS: each lane
// fetches its MFMA A-fragment directly from global (L2-hot: 256KB t2 slice
// shared by the 4 co-XCD blocks of batch b), software-pipelined one ks
// ahead. B (weights) double-buffered in LDS (2 x 34KB); stage-writes of
// tile kt+1 overlap the MFMA clusters of tile kt; ONE lgkm+barrier per
// iteration; B-loads for kt+2 issue-pinned before the barrier.
template <bool USE_PERM>
__global__ __launch_bounds__(512, 4) void pdot_kernel(
    const float* __restrict__ t1, const float* __restrict__ t2,
    const int* __restrict__ pidx, const float* __restrict__ wgt,
    const int* __restrict__ perm, float* __restrict__ out)
{
    __shared__ unsigned short sB[2][BI * LDSTB];   // 2 x 34 KB

    const int g  = blockIdx.x;
    const int x  = g & 7;                 // XCD
    const int s  = g >> 3;                // per-XCD sequence
    const int slot = x * 32 + (s >> 2);   // expert-sorted batch slot
    const int b  = USE_PERM ? perm[slot] : slot;
    const int it = s & 3;
    const int i0 = it * BI;

    const int t  = threadIdx.x;
    const int w  = t >> 6;         // wave 0..7
    const int wv = w & 3;          // l-group: rows wv*32..wv*32+31
    const int ih = w >> 2;         // i-half: cols ih*64..ih*64+63 of the tile
    const int ln = t & 63;
    const int nh = ln & 15;
    const int qd = ln >> 4;

    const int e = pidx[b];
    const float* aPtr = t2  + (size_t)b * (NL * ND2);
    const float* bPtr = wgt + (size_t)e * (ND1 * ND2) + (size_t)i0 * ND2;
    const float* t1p  = t1  + (size_t)b * (NL * ND1) + i0 + ih * 64;

    // per-lane A-fragment base: rows wv*32+nh and +16, col qd*8
    const float* aF0 = aPtr + (size_t)(wv * 32 + nh) * ND2 + qd * 8;
    const float* aF1 = aF0 + (size_t)16 * ND2;

    float4_t acc[2][4];
    #pragma unroll
    for (int i = 0; i < 2; ++i)
        #pragma unroll
        for (int j = 0; j < 4; ++j) {
            float4_t z = {0.f, 0.f, 0.f, 0.f};
            acc[i][j] = z;
        }

    // B staging map: tile 128 rows x 128 cols fp32 = 4096 float4; 512 thr
    // -> 8 each. lane (t&31) owns float4-col (t&31), row = p*16 + (t>>5).
    const int r_row = t >> 5;            // 0..15, +p*16
    const int c4    = (t & 31) * 4;      // float col
    const size_t bOff = (size_t)r_row * ND2 + c4;
    const int wOffB = r_row * LDSTB + c4;

    float4_t pb[8];   // in-flight B prefetch (32 VGPRs)

    // ---- prologue: stage B tile 0 into buf0; issue loads of tile 1 ----
    #pragma unroll
    for (int p = 0; p < 8; ++p)
        pb[p] = *(const float4_t*)(bPtr + bOff + (size_t)p * (16 * ND2));
    #pragma unroll
    for (int p = 0; p < 8; ++p)
        *(ushort4_t*)(&sB[0][wOffB + p * (16 * LDSTB)]) = cvt4(pb[p]);
    #pragma unroll
    for (int p = 0; p < 8; ++p)
        pb[p] = *(const float4_t*)(bPtr + bOff + BK + (size_t)p * (16 * ND2));
    __builtin_amdgcn_sched_barrier(0);
    asm volatile("s_waitcnt lgkmcnt(0)" ::: "memory");
    __builtin_amdgcn_sched_barrier(0);
    __builtin_amdgcn_s_barrier();
    __builtin_amdgcn_sched_barrier(0);

    #pragma unroll
    for (int kt = 0; kt < NKT; ++kt) {
        const int cur = kt & 1;
        const int nxt = cur ^ 1;
        const unsigned short* cB = &sB[cur][0];
        const int kbase = kt * BK;

        // A-fragment pipeline: load ks=0
        float4_t a00 = *(const float4_t*)(aF0 + kbase);
        float4_t a01 = *(const float4_t*)(aF0 + kbase + 4);
        float4_t a10 = *(const float4_t*)(aF1 + kbase);
        float4_t a11 = *(const float4_t*)(aF1 + kbase + 4);

        #pragma unroll
        for (int ks = 0; ks < 4; ++ks) {
            const int kf = ks * 32 + qd * 8;
            // B fragments from LDS
            bf16x8_t bv[4];
            #pragma unroll
            for (int ns = 0; ns < 4; ++ns)
                bv[ns] = __builtin_bit_cast(bf16x8_t, *(const ushort8_t*)(&cB[(ih * 64 + ns * 16 + nh) * LDSTB + kf]));
            // current A fragments
            bf16x8_t af0 = cvt8(a00, a01);
            bf16x8_t af1 = cvt8(a10, a11);
            // issue next ks A-loads before MFMA (L2 latency hides under MFMA)
            if (ks < 3) {
                const int kn = kbase + (ks + 1) * 32;
                a00 = *(const float4_t*)(aF0 + kn);
                a01 = *(const float4_t*)(aF0 + kn + 4);
                a10 = *(const float4_t*)(aF1 + kn);
                a11 = *(const float4_t*)(aF1 + kn + 4);
            }
            __builtin_amdgcn_s_setprio(1);
            #pragma unroll
            for (int ns = 0; ns < 4; ++ns) {
                acc[0][ns] = __builtin_amdgcn_mfma_f32_16x16x32_bf16(af0, bv[ns], acc[0][ns], 0, 0, 0);
                acc[1][ns] = __builtin_amdgcn_mfma_f32_16x16x32_bf16(af1, bv[ns], acc[1][ns], 0, 0, 0);
            }
            __builtin_amdgcn_s_setprio(0);

            // overlapped B-stage of tile kt+1 into buf nxt, split across ks
            if (kt < NKT - 1) {
                if (ks == 1) {
                    #pragma unroll
                    for (int p = 0; p < 4; ++p)
                        *(ushort4_t*)(&sB[nxt][wOffB + p * (16 * LDSTB)]) = cvt4(pb[p]);
                } else if (ks == 2) {
                    #pragma unroll
                    for (int p = 4; p < 8; ++p)
                        *(ushort4_t*)(&sB[nxt][wOffB + p * (16 * LDSTB)]) = cvt4(pb[p]);
                }
            }
        }

        // issue B loads for tile kt+2 (pinned: cannot sink below)
        if (kt < NKT - 2) {
            const size_t k0 = (size_t)(kt + 2) * BK;
            #pragma unroll
            for (int p = 0; p < 8; ++p)
                pb[p] = *(const float4_t*)(bPtr + bOff + k0 + (size_t)p * (16 * ND2));
            __builtin_amdgcn_sched_barrier(0);
        }
        if (kt < NKT - 1) {
            asm volatile("s_waitcnt lgkmcnt(0)" ::: "memory");
            __builtin_amdgcn_sched_barrier(0);
            __builtin_amdgcn_s_barrier();
            __builtin_amdgcn_sched_barrier(0);
        }
    }

    // epilogue: out[b,l] += sum over this wave's i-columns of Z[l,i]*t1[l,i]
    // C/D: col(n=i) = ih*64 + ns*16 + nh, row(m=l) = wv*32 + ms*16 + qd*4 + r
    #pragma unroll
    for (int ms = 0; ms < 2; ++ms) {
        #pragma unroll
        for (int r = 0; r < 4; ++r) {
            const int row = wv * 32 + ms * 16 + qd * 4 + r;
            float ps = 0.f;
            #pragma unroll
            for (int ns = 0; ns < 4; ++ns) {
                const float tv = t1p[(size_t)row * ND1 + ns * 16 + nh];
                ps += acc[ms][ns][r] * tv;
            }
            ps += __shfl_xor(ps, 1);
            ps += __shfl_xor(ps, 2);
            ps += __shfl_xor(ps, 4);
            ps += __shfl_xor(ps, 8);
            if (nh == 0) atomicAdd(&out[b * NL + row], ps);
        }
    }
}

extern "C" void kernel_launch(void* const* d_in, const int* in_sizes, int n_in,
                              void* d_out, int out_size, void* d_ws, size_t ws_size,
                              hipStream_t stream)
{
    const float* t1  = (const float*)d_in[0];
    const float* t2  = (const float*)d_in[1];
    const int* pidx  = (const int*)d_in[2];
    const float* wgt = (const float*)d_in[3];
    float* out = (float*)d_out;

    const int zero_blocks = (out_size + 255) / 256;
    const bool have_ws = ws_size >= NB * sizeof(int);
    int* perm = have_ws ? (int*)d_ws : nullptr;

    pre_kernel<<<dim3(zero_blocks), dim3(256), 0, stream>>>(pidx, perm, out, out_size, have_ws ? 1 : 0);

    if (have_ws)
        pdot_kernel<true><<<dim3(NB * (ND1 / BI)), dim3(512), 0, stream>>>(t1, t2, pidx, wgt, perm, out);
    else
        pdot_kernel<false><<<dim3(NB * (ND1 / BI)), dim3(512), 0, stream>>>(t1, t2, pidx, wgt, nullptr, out);
}